// Round 1
// baseline (1146.031 us; speedup 1.0000x reference)
//
#include <hip/hip_runtime.h>

#define B_  8
#define LV_ 4096
#define D_  256
#define N_  2048
#define P_  32

// One 64-lane wave per (box n, bin p). Lane l owns channels [4l, 4l+4) as float4.
// All sample math (y, y_lo, weights) is wave-uniform -> scalar-friendly, no divergence.
// Row-walk register reuse: y_lo advances by 0 or 1 per sample (sub <= 1), so vhi
// shifts into vlo and we issue ~1 row load per sample instead of 2.
__global__ __launch_bounds__(64) void roi_align1d_kernel(
    const float* __restrict__ feat,       // [B, LV, D]
    const float* __restrict__ boxes,      // [N, 2]
    const int*   __restrict__ batch_idx,  // [N]
    float*       __restrict__ out)        // [N, P, D]
{
    const int nb   = blockIdx.x;      // n*P + p
    const int n    = nb >> 5;
    const int p    = nb & (P_ - 1);
    const int lane = threadIdx.x;     // 0..63

    const float y1    = boxes[2 * n];
    const float y2    = boxes[2 * n + 1];
    const float bin_h = (y2 - y1) * (1.0f / (float)P_);
    const int   grid_h = (int)ceilf(bin_h);
    const int   cnt    = grid_h > 1 ? grid_h : 1;
    const float sub     = bin_h / (float)cnt;
    const float inv_cnt = 1.0f / (float)cnt;
    const float bin_off = (y1 - 0.5f) + (float)p * bin_h;

    const long    base  = (long)batch_idx[n] * LV_;
    const float4* featv = (const float4*)feat;   // row stride D_/4 = 64 float4

    float4 acc = make_float4(0.f, 0.f, 0.f, 0.f);
    float4 vlo = acc, vhi = acc;
    int cur_lo = -100;

    for (int g = 0; g < grid_h; ++g) {
        const float y  = bin_off + ((float)g + 0.5f) * sub;
        const float yc = fmaxf(y, 0.0f);
        int   lo = (int)floorf(yc);
        int   hi;
        float ly;
        if (lo >= LV_ - 1) {            // hi_case: clamp to last row, ly = 0
            lo = LV_ - 1; hi = LV_ - 1; ly = 0.0f;
        } else {
            hi = lo + 1;  ly = yc - (float)lo;
        }
        const bool  valid = (y >= -1.0f) && (y <= (float)LV_);
        const float w1 = valid ? ly : 0.0f;
        const float w0 = valid ? (1.0f - ly) : 0.0f;

        if (lo != cur_lo) {             // wave-uniform branch
            vlo = (lo == cur_lo + 1) ? vhi
                                     : featv[(base + lo) * 64 + lane];
            vhi = (hi != lo) ? featv[(base + hi) * 64 + lane] : vlo;
            cur_lo = lo;
        }

        acc.x = fmaf(w0, vlo.x, acc.x);
        acc.y = fmaf(w0, vlo.y, acc.y);
        acc.z = fmaf(w0, vlo.z, acc.z);
        acc.w = fmaf(w0, vlo.w, acc.w);
        acc.x = fmaf(w1, vhi.x, acc.x);
        acc.y = fmaf(w1, vhi.y, acc.y);
        acc.z = fmaf(w1, vhi.z, acc.z);
        acc.w = fmaf(w1, vhi.w, acc.w);
    }

    acc.x *= inv_cnt;
    acc.y *= inv_cnt;
    acc.z *= inv_cnt;
    acc.w *= inv_cnt;

    ((float4*)out)[(long)nb * 64 + lane] = acc;
}

extern "C" void kernel_launch(void* const* d_in, const int* in_sizes, int n_in,
                              void* d_out, int out_size, void* d_ws, size_t ws_size,
                              hipStream_t stream) {
    const float* feat      = (const float*)d_in[0];
    const float* boxes     = (const float*)d_in[1];
    const int*   batch_idx = (const int*)d_in[2];
    float*       out       = (float*)d_out;

    dim3 grid(N_ * P_);   // 65536 blocks, one wave each
    dim3 block(64);
    roi_align1d_kernel<<<grid, block, 0, stream>>>(feat, boxes, batch_idx, out);
}